// Round 1
// baseline (242.600 us; speedup 1.0000x reference)
//
#include <hip/hip_runtime.h>
#include <math.h>

#define NNODES 10000
#define BATCH  32
#define DDIM   512
#define KSEL   5000
#define EPSV   1e-8f
#define CHUNK  250

// Monotone map: float ordering -> unsigned ordering
__device__ __forceinline__ unsigned mapf(float f) {
    unsigned u = __float_as_uint(f);
    return (u & 0x80000000u) ? ~u : (u | 0x80000000u);
}

// K0: w = v/||v||, zero d_out
__global__ __launch_bounds__(512) void prep_kernel(const float* __restrict__ v,
                                                   float* __restrict__ w,
                                                   float* __restrict__ out, int outn) {
    __shared__ float red[8];
    __shared__ float nrm;
    int tid = threadIdx.x;
    float val = v[tid];
    float sq = val * val;
    for (int off = 32; off > 0; off >>= 1) sq += __shfl_down(sq, off);
    if ((tid & 63) == 0) red[tid >> 6] = sq;
    __syncthreads();
    if (tid == 0) {
        float s = 0.f;
        for (int i = 0; i < 8; i++) s += red[i];
        nrm = sqrtf(s) + EPSV;
    }
    __syncthreads();
    w[tid] = val / nrm;
    for (int i = tid; i < outn; i += 512) out[i] = 0.f;
}

// K1: raw[node] = dot(x[node,:], w)  -- one wave per node
__global__ __launch_bounds__(256) void score_kernel(const float* __restrict__ x,
                                                    const float* __restrict__ w,
                                                    float* __restrict__ raw, int total) {
    int wave = (blockIdx.x * 256 + threadIdx.x) >> 6;
    int lane = threadIdx.x & 63;
    if (wave >= total) return;
    const float4* xp = (const float4*)(x + (size_t)wave * DDIM);
    const float4* wp = (const float4*)w;
    float4 a0 = xp[lane], a1 = xp[lane + 64];
    float4 b0 = wp[lane], b1 = wp[lane + 64];
    float d = a0.x * b0.x + a0.y * b0.y + a0.z * b0.z + a0.w * b0.w
            + a1.x * b1.x + a1.y * b1.y + a1.z * b1.z + a1.w * b1.w;
    for (int off = 32; off > 0; off >>= 1) d += __shfl_down(d, off);
    if (lane == 0) raw[wave] = d;
}

// K2: per-batch stats, K-th-largest threshold (binary search), loss, weight mask
__global__ __launch_bounds__(1024) void select_kernel(const float* __restrict__ raw,
                                                      float* __restrict__ weight,
                                                      float* __restrict__ loss_out) {
    __shared__ float s[NNODES];
    __shared__ float fredA[16], fredB[16];
    __shared__ unsigned ired[16];
    __shared__ unsigned eq_idx[128];
    __shared__ int eq_cnt;
    __shared__ float fb[2];
    __shared__ unsigned ub[2];

    const int tid = threadIdx.x;
    const int lane = tid & 63;
    const int wid = tid >> 6;
    const int b = blockIdx.x;
    const float* rb = raw + (size_t)b * NNODES;
    float* wb = weight + (size_t)b * NNODES;

    float sum = 0.f, sumsq = 0.f;
    for (int i = tid; i < NNODES; i += 1024) {
        float v = rb[i];
        s[i] = v;
        sum += v; sumsq += v * v;
    }
    for (int off = 32; off > 0; off >>= 1) {
        sum += __shfl_down(sum, off);
        sumsq += __shfl_down(sumsq, off);
    }
    if (lane == 0) { fredA[wid] = sum; fredB[wid] = sumsq; }
    if (tid == 0) eq_cnt = 0;
    __syncthreads();
    if (tid == 0) {
        float ts = 0.f, tq = 0.f;
        for (int i = 0; i < 16; i++) { ts += fredA[i]; tq += fredB[i]; }
        float mu = ts / (float)NNODES;
        float var = tq / (float)NNODES - mu * mu;
        float sd = sqrtf(fmaxf(var, 0.f));
        fb[0] = mu; fb[1] = 1.f / (sd + EPSV);
    }
    __syncthreads();
    const float mu = fb[0], inv = fb[1];

    // binary search for largest t with count(mapf >= t) >= K  (== K-th largest)
    unsigned long long lo = 0ull, hi = 0xFFFFFFFFull;
    while (lo < hi) {
        unsigned mid = (unsigned)((lo + hi + 1ull) >> 1);
        unsigned c = 0;
        for (int i = tid; i < NNODES; i += 1024) c += (mapf(s[i]) >= mid) ? 1u : 0u;
        for (int off = 32; off > 0; off >>= 1) c += __shfl_down(c, off);
        if (lane == 0) ired[wid] = c;
        __syncthreads();
        if (tid == 0) { unsigned t = 0; for (int i = 0; i < 16; i++) t += ired[i]; ub[0] = t; }
        __syncthreads();
        unsigned total = ub[0];
        if (total >= (unsigned)KSEL) lo = mid; else hi = (unsigned long long)mid - 1ull;
        __syncthreads();
    }
    const unsigned tu = (unsigned)lo;

    // count strictly-greater
    unsigned cg = 0;
    for (int i = tid; i < NNODES; i += 1024) cg += (mapf(s[i]) > tu) ? 1u : 0u;
    for (int off = 32; off > 0; off >>= 1) cg += __shfl_down(cg, off);
    if (lane == 0) ired[wid] = cg;
    __syncthreads();
    if (tid == 0) { unsigned t = 0; for (int i = 0; i < 16; i++) t += ired[i]; ub[1] = t; }
    __syncthreads();
    const unsigned count_gt = ub[1];

    // loss + weights; collect tied-at-threshold indices
    float l = 0.f;
    for (int i = tid; i < NNODES; i += 1024) {
        float v = s[i];
        unsigned m = mapf(v);
        float z = (v - mu) * inv;
        float sig = 1.f / (1.f + expf(-z));
        float wt = 0.f;
        if (m > tu) { l += logf(sig + EPSV); wt = sig; }
        else if (m < tu) { l += logf(1.f - sig + EPSV); }
        else { int p = atomicAdd(&eq_cnt, 1); if (p < 128) eq_idx[p] = (unsigned)i; }
        wb[i] = wt;
    }
    for (int off = 32; off > 0; off >>= 1) l += __shfl_down(l, off);
    if (lane == 0) fredA[wid] = l;
    __syncthreads();
    if (tid == 0) {
        float tl = 0.f;
        for (int i = 0; i < 16; i++) tl += fredA[i];
        int ce = eq_cnt;
        int stored = ce > 128 ? 128 : ce;
        // sort tied indices ascending (jax top_k prefers lower index)
        for (int i = 1; i < stored; i++) {
            unsigned key = eq_idx[i]; int j = i - 1;
            while (j >= 0 && eq_idx[j] > key) { eq_idx[j + 1] = eq_idx[j]; j--; }
            eq_idx[j + 1] = key;
        }
        int ne = KSEL - (int)count_gt;  // how many ties go to top-k
        for (int p = 0; p < stored; p++) {
            unsigned idx = eq_idx[p];
            float v = s[idx];
            float z = (v - mu) * inv;
            float sig = 1.f / (1.f + expf(-z));
            if (p < ne) { tl += logf(sig + EPSV); wb[idx] = sig; }
            else        { tl += logf(1.f - sig + EPSV); }
        }
        if (ce > stored) {
            float v = s[eq_idx[0]];
            float z = (v - mu) * inv;
            float sig = 1.f / (1.f + expf(-z));
            tl += (float)(ce - stored) * logf(1.f - sig + EPSV);
        }
        float loss_b = -tl / (float)NNODES;
        atomicAdd(loss_out, loss_b / (float)BATCH);
    }
}

// K3: pooled[b,:] += (1/K) * sum_{selected n in chunk} weight[n] * x[b,n,:]
__global__ __launch_bounds__(128) void pool_kernel(const float* __restrict__ x,
                                                   const float* __restrict__ weight,
                                                   float* __restrict__ out) {
    __shared__ float swt[CHUNK];
    const int chunks = NNODES / CHUNK;  // 40
    const int b = blockIdx.x / chunks;
    const int c = blockIdx.x % chunks;
    const int n0 = c * CHUNK;
    const int tid = threadIdx.x;
    const float* wb = weight + (size_t)b * NNODES + n0;
    for (int i = tid; i < CHUNK; i += 128) swt[i] = wb[i];
    __syncthreads();
    const float4* xb = (const float4*)x + ((size_t)b * NNODES + n0) * (DDIM / 4);
    float4 acc = {0.f, 0.f, 0.f, 0.f};
    for (int n = 0; n < CHUNK; n++) {
        float wt = swt[n];
        if (wt != 0.f) {  // block-uniform branch: skip unselected node's 2KB
            float4 xv = xb[(size_t)n * (DDIM / 4) + tid];
            acc.x += xv.x * wt; acc.y += xv.y * wt;
            acc.z += xv.z * wt; acc.w += xv.w * wt;
        }
    }
    const float scale = 1.f / (float)KSEL;
    float* o = out + b * DDIM + tid * 4;
    atomicAdd(o + 0, acc.x * scale);
    atomicAdd(o + 1, acc.y * scale);
    atomicAdd(o + 2, acc.z * scale);
    atomicAdd(o + 3, acc.w * scale);
}

extern "C" void kernel_launch(void* const* d_in, const int* in_sizes, int n_in,
                              void* d_out, int out_size, void* d_ws, size_t ws_size,
                              hipStream_t stream) {
    const float* x = (const float*)d_in[0];   // (B*N, D) fp32
    const float* v = (const float*)d_in[1];   // (D, 1) fp32
    float* out = (float*)d_out;               // pooled (B*D) then loss (1)

    float* w      = (float*)d_ws;             // 512
    float* raw    = w + DDIM;                 // B*N
    float* weight = raw + BATCH * NNODES;     // B*N

    prep_kernel<<<1, DDIM, 0, stream>>>(v, w, out, out_size);
    int total = BATCH * NNODES;
    score_kernel<<<total / 4, 256, 0, stream>>>(x, w, raw, total);
    select_kernel<<<BATCH, 1024, 0, stream>>>(raw, weight, out + BATCH * DDIM);
    pool_kernel<<<BATCH * (NNODES / CHUNK), 128, 0, stream>>>(x, weight, out);
}

// Round 2
// 183.524 us; speedup vs baseline: 1.3219x; 1.3219x over previous
//
#include <hip/hip_runtime.h>
#include <math.h>

#define NNODES 10000
#define BATCH  32
#define DDIM   512
#define KSEL   5000
#define EPSV   1e-8f
#define SPAN   125

// Monotone map: float ordering -> unsigned ordering
__device__ __forceinline__ unsigned mapf(float f) {
    unsigned u = __float_as_uint(f);
    return (u & 0x80000000u) ? ~u : (u | 0x80000000u);
}

// K0: w = v/||v||, zero loss slot
__global__ __launch_bounds__(512) void prep_kernel(const float* __restrict__ v,
                                                   float* __restrict__ w,
                                                   float* __restrict__ loss_out) {
    __shared__ float red[8];
    __shared__ float nrm;
    int tid = threadIdx.x;
    float val = v[tid];
    float sq = val * val;
    for (int off = 32; off > 0; off >>= 1) sq += __shfl_down(sq, off);
    if ((tid & 63) == 0) red[tid >> 6] = sq;
    __syncthreads();
    if (tid == 0) {
        float s = 0.f;
        for (int i = 0; i < 8; i++) s += red[i];
        nrm = sqrtf(s) + EPSV;
        *loss_out = 0.f;
    }
    __syncthreads();
    w[tid] = val / nrm;
}

// K1: raw[node] = dot(x[node,:], w)  -- one wave per node
__global__ __launch_bounds__(256) void score_kernel(const float* __restrict__ x,
                                                    const float* __restrict__ w,
                                                    float* __restrict__ raw, int total) {
    int wave = (blockIdx.x * 256 + threadIdx.x) >> 6;
    int lane = threadIdx.x & 63;
    if (wave >= total) return;
    const float4* xp = (const float4*)(x + (size_t)wave * DDIM);
    const float4* wp = (const float4*)w;
    float4 a0 = xp[lane], a1 = xp[lane + 64];
    float4 b0 = wp[lane], b1 = wp[lane + 64];
    float d = a0.x * b0.x + a0.y * b0.y + a0.z * b0.z + a0.w * b0.w
            + a1.x * b1.x + a1.y * b1.y + a1.z * b1.z + a1.w * b1.w;
    for (int off = 32; off > 0; off >>= 1) d += __shfl_down(d, off);
    if (lane == 0) raw[wave] = d;
}

// One radix level: histogram candidates (prefix-matched) into nbins on bits
// [shift .. shift+log2(nbins)), then find bin of the k-th largest.
// res[0] = bin index, res[1] = count strictly above that bin (within candidates).
__device__ void radix_level(const float* __restrict__ s, unsigned* hist, unsigned* segsum,
                            unsigned prefix, int prefshift, int shift, int nbins,
                            unsigned k, unsigned* res, int tid) {
    for (int i = tid; i < nbins; i += 1024) hist[i] = 0;
    __syncthreads();
    for (int i = tid; i < NNODES; i += 1024) {
        unsigned u = mapf(s[i]);
        bool cand = (prefshift >= 32) || ((u >> prefshift) == prefix);
        if (cand) atomicAdd(&hist[(u >> shift) & (unsigned)(nbins - 1)], 1u);
    }
    __syncthreads();
    int nseg = nbins >> 5;
    if (tid < nseg) {
        unsigned ssum = 0;
        for (int j = 0; j < 32; j++) ssum += hist[(tid << 5) + j];
        segsum[tid] = ssum;
    }
    __syncthreads();
    if (tid == 0) {
        unsigned cum = 0;
        int seg = 0;
        for (int i = nseg - 1; i >= 0; i--) {
            if (cum + segsum[i] >= k) { seg = i; break; }
            cum += segsum[i];
        }
        int bin = seg << 5;
        for (int j = 31; j >= 0; j--) {
            unsigned h = hist[(seg << 5) + j];
            if (cum + h >= k) { bin = (seg << 5) + j; break; }
            cum += h;
        }
        res[0] = (unsigned)bin;
        res[1] = cum;
    }
    __syncthreads();
}

// K2: per-batch stats, radix-select K-th largest, loss, compacted (idx, wt) list.
// Also zeroes this batch's pooled output slice.
__global__ __launch_bounds__(1024) void select_kernel(const float* __restrict__ raw,
                                                      int* __restrict__ sel_idx,
                                                      float* __restrict__ sel_wt,
                                                      float* __restrict__ out_pooled,
                                                      float* __restrict__ loss_out) {
    __shared__ float s[NNODES];
    __shared__ unsigned hist[2048];
    __shared__ unsigned segsum[64];
    __shared__ float fredA[16], fredB[16];
    __shared__ unsigned eq_idx[128];
    __shared__ int eq_cnt;
    __shared__ int sel_cnt;
    __shared__ float fb[2];
    __shared__ unsigned res[2];

    const int tid = threadIdx.x;
    const int lane = tid & 63;
    const int wid = tid >> 6;
    const int b = blockIdx.x;
    const float* rb = raw + (size_t)b * NNODES;
    int* sib = sel_idx + (size_t)b * KSEL;
    float* swb = sel_wt + (size_t)b * KSEL;

    // zero this batch's pooled slice (pool kernel atomically accumulates later)
    for (int i = tid; i < DDIM; i += 1024) out_pooled[(size_t)b * DDIM + i] = 0.f;

    float sum = 0.f, sumsq = 0.f;
    for (int i = tid; i < NNODES; i += 1024) {
        float v = rb[i];
        s[i] = v;
        sum += v; sumsq += v * v;
    }
    for (int off = 32; off > 0; off >>= 1) {
        sum += __shfl_down(sum, off);
        sumsq += __shfl_down(sumsq, off);
    }
    if (lane == 0) { fredA[wid] = sum; fredB[wid] = sumsq; }
    if (tid == 0) { eq_cnt = 0; sel_cnt = 0; }
    __syncthreads();
    if (tid == 0) {
        float ts = 0.f, tq = 0.f;
        for (int i = 0; i < 16; i++) { ts += fredA[i]; tq += fredB[i]; }
        float mu = ts / (float)NNODES;
        float var = tq / (float)NNODES - mu * mu;
        float sd = sqrtf(fmaxf(var, 0.f));
        fb[0] = mu; fb[1] = 1.f / (sd + EPSV);
    }
    __syncthreads();
    const float mu = fb[0], inv = fb[1];

    // 3-level radix select: bits [31:21], [20:10], [9:0]
    radix_level(s, hist, segsum, 0u, 32, 21, 2048, (unsigned)KSEL, res, tid);
    unsigned t1 = res[0];
    unsigned cg = res[1];
    unsigned k1 = (unsigned)KSEL - cg;
    radix_level(s, hist, segsum, t1, 21, 10, 2048, k1, res, tid);
    unsigned t2 = res[0];
    cg += res[1];
    unsigned k2 = k1 - res[1];
    unsigned p2 = (t1 << 11) | t2;
    radix_level(s, hist, segsum, p2, 10, 0, 1024, k2, res, tid);
    unsigned t3 = res[0];
    cg += res[1];
    const unsigned tu = (p2 << 10) | t3;
    const unsigned count_gt = cg;

    // loss + compaction; collect tied-at-threshold indices
    float l = 0.f;
    for (int i = tid; i < NNODES; i += 1024) {
        float v = s[i];
        unsigned m = mapf(v);
        float z = (v - mu) * inv;
        float sig = 1.f / (1.f + expf(-z));
        if (m > tu) {
            l += logf(sig + EPSV);
            int p = atomicAdd(&sel_cnt, 1);
            sib[p] = i; swb[p] = sig;
        } else if (m < tu) {
            l += logf(1.f - sig + EPSV);
        } else {
            int p = atomicAdd(&eq_cnt, 1);
            if (p < 128) eq_idx[p] = (unsigned)i;
        }
    }
    for (int off = 32; off > 0; off >>= 1) l += __shfl_down(l, off);
    if (lane == 0) fredA[wid] = l;
    __syncthreads();
    if (tid == 0) {
        float tl = 0.f;
        for (int i = 0; i < 16; i++) tl += fredA[i];
        int ce = eq_cnt;
        int stored = ce > 128 ? 128 : ce;
        // sort tied indices ascending (jax top_k prefers lower index)
        for (int i = 1; i < stored; i++) {
            unsigned key = eq_idx[i]; int j = i - 1;
            while (j >= 0 && eq_idx[j] > key) { eq_idx[j + 1] = eq_idx[j]; j--; }
            eq_idx[j + 1] = key;
        }
        int ne = KSEL - (int)count_gt;  // ties that enter the top-k
        int sc = sel_cnt;
        for (int p = 0; p < stored; p++) {
            unsigned idx = eq_idx[p];
            float v = s[idx];
            float z = (v - mu) * inv;
            float sig = 1.f / (1.f + expf(-z));
            if (p < ne) { tl += logf(sig + EPSV); sib[sc] = (int)idx; swb[sc] = sig; sc++; }
            else        { tl += logf(1.f - sig + EPSV); }
        }
        if (ce > stored) {  // pathological mass-tie fallback (never hit for random data)
            float v = s[eq_idx[0]];
            float z = (v - mu) * inv;
            float sig = 1.f / (1.f + expf(-z));
            int extra_sel = ne - stored;
            for (int p = 0; p < extra_sel; p++) { sib[sc] = (int)eq_idx[0]; swb[sc] = sig; sc++; }
            int rest = (ce - stored) - (extra_sel > 0 ? extra_sel : 0);
            tl += (float)rest * logf(1.f - sig + EPSV);
        }
        float loss_b = -tl / (float)NNODES;
        atomicAdd(loss_out, loss_b / (float)BATCH);
    }
}

// K3: pooled[b,:] += (1/K) * sum over a SPAN of the compacted selection list
__global__ __launch_bounds__(128) void pool_kernel(const float* __restrict__ x,
                                                   const int* __restrict__ sel_idx,
                                                   const float* __restrict__ sel_wt,
                                                   float* __restrict__ out) {
    __shared__ int sidx[SPAN];
    __shared__ float swt[SPAN];
    const int spans = KSEL / SPAN;  // 40
    const int b = blockIdx.x / spans;
    const int sp = blockIdx.x % spans;
    const int e0 = sp * SPAN;
    const int tid = threadIdx.x;
    const int* ib = sel_idx + (size_t)b * KSEL + e0;
    const float* wp = sel_wt + (size_t)b * KSEL + e0;
    for (int i = tid; i < SPAN; i += 128) { sidx[i] = ib[i]; swt[i] = wp[i]; }
    __syncthreads();
    const float4* xb = (const float4*)x + (size_t)b * NNODES * (DDIM / 4);
    float4 acc = {0.f, 0.f, 0.f, 0.f};
    for (int e = 0; e < SPAN; e++) {
        int n = sidx[e];
        float wt = swt[e];
        float4 xv = xb[(size_t)n * (DDIM / 4) + tid];
        acc.x += xv.x * wt; acc.y += xv.y * wt;
        acc.z += xv.z * wt; acc.w += xv.w * wt;
    }
    const float scale = 1.f / (float)KSEL;
    float* o = out + b * DDIM + tid * 4;
    atomicAdd(o + 0, acc.x * scale);
    atomicAdd(o + 1, acc.y * scale);
    atomicAdd(o + 2, acc.z * scale);
    atomicAdd(o + 3, acc.w * scale);
}

extern "C" void kernel_launch(void* const* d_in, const int* in_sizes, int n_in,
                              void* d_out, int out_size, void* d_ws, size_t ws_size,
                              hipStream_t stream) {
    const float* x = (const float*)d_in[0];   // (B*N, D) fp32
    const float* v = (const float*)d_in[1];   // (D, 1) fp32
    float* out = (float*)d_out;               // pooled (B*D) then loss (1)

    float* w       = (float*)d_ws;                    // 512
    float* raw     = w + DDIM;                        // B*N
    int*   sel_idx = (int*)(raw + BATCH * NNODES);    // B*K
    float* sel_wt  = (float*)(sel_idx + BATCH * KSEL);// B*K

    prep_kernel<<<1, DDIM, 0, stream>>>(v, w, out + BATCH * DDIM);
    int total = BATCH * NNODES;
    score_kernel<<<total / 4, 256, 0, stream>>>(x, w, raw, total);
    select_kernel<<<BATCH, 1024, 0, stream>>>(raw, sel_idx, sel_wt, out, out + BATCH * DDIM);
    pool_kernel<<<BATCH * (KSEL / SPAN), 128, 0, stream>>>(x, sel_idx, sel_wt, out);
}